// Round 4
// baseline (308.065 us; speedup 1.0000x reference)
//
#include <hip/hip_runtime.h>

typedef __bf16 bf16;
typedef bf16  bf16x8 __attribute__((ext_vector_type(8)));
typedef bf16  bf16x4 __attribute__((ext_vector_type(4)));
typedef short s16x4  __attribute__((ext_vector_type(4)));
typedef float f32x4  __attribute__((ext_vector_type(4)));

#define AS1 __attribute__((address_space(1)))
#define AS3 __attribute__((address_space(3)))

#define SQLEN 2048
#define EMB   1024

// ---------------- fp32 -> bf16 convert (memory-bound) ----------------
__global__ __launch_bounds__(256) void cvt_f32_bf16(const float* __restrict__ in,
                                                    bf16* __restrict__ out, int n8) {
  int i = blockIdx.x * blockDim.x + threadIdx.x;
  if (i >= n8) return;
  const float4* p = (const float4*)in + (size_t)i * 2;
  float4 a = p[0], b = p[1];
  bf16x8 o;
  o[0] = (bf16)a.x; o[1] = (bf16)a.y; o[2] = (bf16)a.z; o[3] = (bf16)a.w;
  o[4] = (bf16)b.x; o[5] = (bf16)b.y; o[6] = (bf16)b.z; o[7] = (bf16)b.w;
  *((bf16x8*)out + i) = o;
}

// 4 weight matrices in one dispatch (blockIdx.y selects)
__global__ __launch_bounds__(256) void cvt_w4(const float* __restrict__ w0, const float* __restrict__ w1,
                                              const float* __restrict__ w2, const float* __restrict__ w3,
                                              bf16* o0, bf16* o1, bf16* o2, bf16* o3, int n8) {
  const float* in; bf16* out;
  switch (blockIdx.y) {
    case 0: in = w0; out = o0; break;
    case 1: in = w1; out = o1; break;
    case 2: in = w2; out = o2; break;
    default: in = w3; out = o3; break;
  }
  int i = blockIdx.x * blockDim.x + threadIdx.x;
  if (i >= n8) return;
  const float4* p = (const float4*)in + (size_t)i * 2;
  float4 a = p[0], b = p[1];
  bf16x8 o;
  o[0] = (bf16)a.x; o[1] = (bf16)a.y; o[2] = (bf16)a.z; o[3] = (bf16)a.w;
  o[4] = (bf16)b.x; o[5] = (bf16)b.y; o[6] = (bf16)b.z; o[7] = (bf16)b.w;
  *((bf16x8*)out + i) = o;
}

// ---------------- V transpose: Vb[b*2048+t][n] -> Vt[(b*1024+n)][t] ----------
__global__ __launch_bounds__(256) void transpose_v(const bf16* __restrict__ Vb,
                                                   bf16* __restrict__ Vt) {
  __shared__ bf16 T[64][72];
  const int b = blockIdx.z;
  const int t0 = blockIdx.x * 64, n0 = blockIdx.y * 64;
  const int r = threadIdx.x >> 3, c = threadIdx.x & 7;
#pragma unroll
  for (int i = 0; i < 2; ++i) {
    const int row = i * 32 + r;
    *(bf16x8*)&T[row][c * 8] =
        *(const bf16x8*)&Vb[((size_t)(b * SQLEN + t0 + row)) * EMB + n0 + c * 8];
  }
  __syncthreads();
#pragma unroll
  for (int i = 0; i < 2; ++i) {
    const int n = i * 32 + r;
    bf16x8 o;
#pragma unroll
    for (int j = 0; j < 8; ++j) o[j] = T[c * 8 + j][n];
    *(bf16x8*)&Vt[((size_t)(b * EMB + n0 + n)) * SQLEN + t0 + c * 8] = o;
  }
}

// ---------------- NT GEMM body: C[M,N] = A[M,K]*B[N,K]^T, dbuf single-barrier K-loop
template <int OUTF32>
__device__ __forceinline__
void gemm_body(const bf16* __restrict__ A, const bf16* __restrict__ B,
               float* __restrict__ Cf, bf16* __restrict__ Cb,
               int M, int N, int K, float scale, bf16* Asl, bf16* Bsl) {
  const int tid  = threadIdx.x;
  const int lane = tid & 63, wave = tid >> 6;
  const int quad = lane >> 4, col = lane & 15;
  const int m0 = blockIdx.x * 128, n0 = blockIdx.y * 128;
  const int wr = wave >> 1, wc = wave & 1;

  f32x4 acc[4][4];
  const f32x4 fz = {0.f, 0.f, 0.f, 0.f};
#pragma unroll
  for (int i = 0; i < 4; ++i)
#pragma unroll
    for (int j = 0; j < 4; ++j) acc[i][j] = fz;

  const int srow = lane >> 2;
  const int sk   = lane & 3;

  auto stage = [&](int buf, int k0) {
#pragma unroll
    for (int r = 0; r < 2; ++r) {
      const int c      = wave * 2 + r;
      const int row    = c * 16 + srow;
      const int gchunk = sk ^ (row & 3);
      const bf16* ga = A + (size_t)(m0 + row) * K + k0 + gchunk * 8;
      const bf16* gb = B + (size_t)(n0 + row) * K + k0 + gchunk * 8;
      __builtin_amdgcn_global_load_lds((const AS1 void*)ga, (AS3 void*)(Asl + buf * 4096 + c * 512), 16, 0, 0);
      __builtin_amdgcn_global_load_lds((const AS1 void*)gb, (AS3 void*)(Bsl + buf * 4096 + c * 512), 16, 0, 0);
    }
  };

  const int nk = K >> 5;
  stage(0, 0);
  for (int it = 0; it < nk; ++it) {
    __syncthreads();
    if (it + 1 < nk) stage((it + 1) & 1, (it + 1) << 5);
    const bf16* As = Asl + (it & 1) * 4096;
    const bf16* Bs = Bsl + (it & 1) * 4096;

    bf16x8 af[4], bfr[4];
#pragma unroll
    for (int i = 0; i < 4; ++i) {
      const int r = wr * 64 + i * 16 + col;
      af[i] = *(const bf16x8*)&As[r * 32 + ((quad ^ (col & 3)) * 8)];
    }
#pragma unroll
    for (int j = 0; j < 4; ++j) {
      const int r = wc * 64 + j * 16 + col;
      bfr[j] = *(const bf16x8*)&Bs[r * 32 + ((quad ^ (col & 3)) * 8)];
    }
#pragma unroll
    for (int i = 0; i < 4; ++i)
#pragma unroll
      for (int j = 0; j < 4; ++j)
        acc[i][j] = __builtin_amdgcn_mfma_f32_16x16x32_bf16(af[i], bfr[j], acc[i][j], 0, 0, 0);
  }

#pragma unroll
  for (int i = 0; i < 4; ++i) {
#pragma unroll
    for (int j = 0; j < 4; ++j) {
      const int gm0 = m0 + wr * 64 + i * 16 + quad * 4;
      const int gn  = n0 + wc * 64 + j * 16 + col;
#pragma unroll
      for (int r = 0; r < 4; ++r) {
        const size_t idx = (size_t)(gm0 + r) * N + gn;
        if (OUTF32) Cf[idx] = acc[i][j][r] * scale;
        else        Cb[idx] = (bf16)(acc[i][j][r] * scale);
      }
    }
  }
}

// fused Q/K/V projection: blockIdx.z selects weight/output
__global__ __launch_bounds__(256, 2)
void gemm_qkv(const bf16* __restrict__ A, const bf16* __restrict__ Wq,
              const bf16* __restrict__ Wk, const bf16* __restrict__ Wv,
              bf16* Qo, bf16* Ko, bf16* Vo, float qscale) {
  __shared__ bf16 Asl[2 * 4096];
  __shared__ bf16 Bsl[2 * 4096];
  const bf16* B; bf16* C; float sc = 1.0f;
  if (blockIdx.z == 0)      { B = Wq; C = Qo; sc = qscale; }
  else if (blockIdx.z == 1) { B = Wk; C = Ko; }
  else                      { B = Wv; C = Vo; }
  gemm_body<0>(A, B, nullptr, C, 8192, 1024, 1024, sc, Asl, Bsl);
}

__global__ __launch_bounds__(256, 2)
void gemm_o(const bf16* __restrict__ A, const bf16* __restrict__ W, float* __restrict__ C) {
  __shared__ bf16 Asl[2 * 4096];
  __shared__ bf16 Bsl[2 * 4096];
  gemm_body<1>(A, W, C, nullptr, 8192, 1024, 1024, 1.0f, Asl, Bsl);
}

// ---------------- flash causal attention, S^T formulation ----------------
// Q-tile 128, 8 waves (512 thr), t-tile 64, K/V double-buffered, 1 barrier/iter.
// Wave w owns q-strip q0+16w+col. LDS 48KB -> 3 blocks/CU (24 waves/CU).
__global__ __launch_bounds__(512, 6)
void attn_flash(const bf16* __restrict__ Q, const bf16* __restrict__ K,
                const bf16* __restrict__ Vt, bf16* __restrict__ Y) {
  __shared__ bf16 Qs[128 * 64];
  __shared__ bf16 Ksb[2][64 * 64];
  __shared__ bf16 Vsb[2][64 * 64];

  const int tid  = threadIdx.x;
  const int lane = tid & 63, wave = tid >> 6;   // wave 0..7
  const int quad = lane >> 4, col = lane & 15;
  const int qt = 15 - blockIdx.x;  // longest blocks first
  const int h  = blockIdx.y;
  const int b  = blockIdx.z;
  const int q0 = qt * 128;
  const int hc = h * 64;
  const size_t rowBase = (size_t)b * SQLEN;

  const int srow8 = lane >> 3;
  const int sch   = lane & 7;
  const int gch   = sch ^ srow8;   // XOR-8 swizzled global chunk
  const int a7    = col & 7;

  auto stageKV = [&](int buf, int t0) {
    const int rr = wave * 8 + srow8;   // 64 rows, 1 instr per wave each
    const bf16* gk = K + (rowBase + t0 + rr) * EMB + hc + gch * 8;
    const bf16* gv = Vt + ((size_t)(b * EMB + hc + rr)) * SQLEN + t0 + gch * 8;
    __builtin_amdgcn_global_load_lds((const AS1 void*)gk, (AS3 void*)(&Ksb[buf][wave * 512]), 16, 0, 0);
    __builtin_amdgcn_global_load_lds((const AS1 void*)gv, (AS3 void*)(&Vsb[buf][wave * 512]), 16, 0, 0);
  };

  // ---- prologue: stage Q (128 rows) + first K/V tile ----
#pragma unroll
  for (int i = 0; i < 2; ++i) {
    const int c  = wave * 2 + i;       // 0..15
    const int rr = c * 8 + srow8;
    const bf16* g = Q + (rowBase + q0 + rr) * EMB + hc + gch * 8;
    __builtin_amdgcn_global_load_lds((const AS1 void*)g, (AS3 void*)(&Qs[c * 512]), 16, 0, 0);
  }
  stageKV(0, 0);
  __syncthreads();
  const bf16x8 qf0 = *(const bf16x8*)&Qs[(wave * 16 + col) * 64 + ((quad ^ a7) * 8)];
  const bf16x8 qf1 = *(const bf16x8*)&Qs[(wave * 16 + col) * 64 + (((quad ^ 4) ^ a7) * 8)];

  float m_i = -INFINITY, l_i = 0.f;
  f32x4 o[4];
  const f32x4 fz = {0.f, 0.f, 0.f, 0.f};
#pragma unroll
  for (int dd = 0; dd < 4; ++dd) o[dd] = fz;

  const int ntt = 2 * qt + 2;
  for (int tt = 0; tt < ntt; ++tt) {
    const int t0 = tt * 64;
    const int cur = tt & 1;
    if (tt + 1 < ntt) stageKV(cur ^ 1, t0 + 64);  // in flight across this iter
    const bf16* Ks = Ksb[cur];
    const bf16* Vs = Vsb[cur];

    // ---- S^T slabs ----
    f32x4 s[4];
#pragma unroll
    for (int sl = 0; sl < 4; ++sl) {
      const bf16x8 kf0 = *(const bf16x8*)&Ks[(sl * 16 + col) * 64 + ((quad ^ a7) * 8)];
      const bf16x8 kf1 = *(const bf16x8*)&Ks[(sl * 16 + col) * 64 + (((quad ^ 4) ^ a7) * 8)];
      f32x4 z = fz;
      z = __builtin_amdgcn_mfma_f32_16x16x32_bf16(kf0, qf0, z, 0, 0, 0);
      s[sl] = __builtin_amdgcn_mfma_f32_16x16x32_bf16(kf1, qf1, z, 0, 0, 0);
    }

    if (tt >= 2 * qt) {  // tiles overlapping the diagonal: global-index mask
      const int qg = q0 + wave * 16 + col;
#pragma unroll
      for (int sl = 0; sl < 4; ++sl)
#pragma unroll
        for (int r = 0; r < 4; ++r)
          if (t0 + sl * 16 + quad * 4 + r > qg) s[sl][r] = -INFINITY;
    }

    // ---- online softmax, exp2 domain, per-lane ----
    float mx = s[0][0];
#pragma unroll
    for (int sl = 0; sl < 4; ++sl)
#pragma unroll
      for (int r = 0; r < 4; ++r) mx = fmaxf(mx, s[sl][r]);
    mx = fmaxf(mx, __shfl_xor(mx, 16));
    mx = fmaxf(mx, __shfl_xor(mx, 32));
    const float mnew  = fmaxf(m_i, mx);
    const float alpha = __builtin_amdgcn_exp2f(m_i - mnew);
    float rs = 0.f;
    bf16x4 pb[4];
#pragma unroll
    for (int sl = 0; sl < 4; ++sl)
#pragma unroll
      for (int r = 0; r < 4; ++r) {
        const float p = __builtin_amdgcn_exp2f(s[sl][r] - mnew);
        rs += p;
        pb[sl][r] = (bf16)p;
      }
    rs += __shfl_xor(rs, 16);
    rs += __shfl_xor(rs, 32);
    l_i = l_i * alpha + rs;
    m_i = mnew;
#pragma unroll
    for (int dd = 0; dd < 4; ++dd) o[dd] *= alpha;

    // ---- O^T += V^T P^T (P straight from registers; k16 MFMA) ----
#pragma unroll
    for (int sl = 0; sl < 4; ++sl) {
      const s16x4 pf = __builtin_bit_cast(s16x4, pb[sl]);
      const int cch  = 2 * sl + (quad >> 1);
      const int half = quad & 1;
#pragma unroll
      for (int dd = 0; dd < 4; ++dd) {
        const int row = dd * 16 + col;
        const bf16x4 vb = *(const bf16x4*)&Vs[row * 64 + ((cch ^ a7) * 8) + half * 4];
        o[dd] = __builtin_amdgcn_mfma_f32_16x16x16bf16_1k(
            __builtin_bit_cast(s16x4, vb), pf, o[dd], 0, 0, 0);
      }
    }
    __syncthreads();  // drains prefetch; guards buffer reuse
  }

  // ---- epilogue: O^T/l -> per-wave transpose (dead Ksb/Vsb storage) -> store ----
  const float rl = __builtin_amdgcn_rcpf(l_i);
  bf16* Ot = (wave < 7) ? (&Ksb[0][0] + wave * 1152) : &Vsb[0][0];  // 16x72 each
#pragma unroll
  for (int dd = 0; dd < 4; ++dd) {
    bf16x4 ob;
#pragma unroll
    for (int r = 0; r < 4; ++r) ob[r] = (bf16)(o[dd][r] * rl);
    *(bf16x4*)&Ot[col * 72 + dd * 16 + quad * 4] = ob;
  }
  // same-wave write->read: ordered by lgkmcnt, no barrier needed
#pragma unroll
  for (int i = 0; i < 2; ++i) {
    const int row = i * 8 + srow8;
    const bf16x8 v = *(const bf16x8*)&Ot[row * 72 + sch * 8];
    *(bf16x8*)&Y[(rowBase + q0 + wave * 16 + row) * EMB + hc + sch * 8] = v;
  }
}

// ---------------- launcher ----------------
extern "C" void kernel_launch(void* const* d_in, const int* in_sizes, int n_in,
                              void* d_out, int out_size, void* d_ws, size_t ws_size,
                              hipStream_t stream) {
  const float* x  = (const float*)d_in[0];
  const float* Wq = (const float*)d_in[1];
  const float* Wk = (const float*)d_in[2];
  const float* Wv = (const float*)d_in[3];
  const float* Wo = (const float*)d_in[4];
  float* out = (float*)d_out;

  const size_t ME = 8192ull * 1024ull;
  const size_t WE = 1024ull * 1024ull;
  bf16* ws  = (bf16*)d_ws;
  bf16* xb  = ws;
  bf16* wqb = xb + ME;
  bf16* wkb = wqb + WE;
  bf16* wvb = wkb + WE;
  bf16* wob = wvb + WE;
  bf16* Qb  = wob + WE;
  bf16* Kb  = Qb + ME;
  bf16* Vb  = Kb + ME;
  bf16* Yb  = Vb + ME;
  bf16* Vtb = xb;        // Vt aliases xb (dead after QKV GEMM)

  cvt_f32_bf16<<<(int)(ME / 8 / 256), 256, 0, stream>>>(x, xb, (int)(ME / 8));
  cvt_w4<<<dim3((int)(WE / 8 / 256), 4), 256, 0, stream>>>(Wq, Wk, Wv, Wo, wqb, wkb, wvb, wob, (int)(WE / 8));

  const float qscale = 0.125f * 1.4426950408889634f;
  gemm_qkv<<<dim3(64, 8, 3), 256, 0, stream>>>(xb, wqb, wkb, wvb, Qb, Kb, Vb, qscale);

  transpose_v<<<dim3(32, 16, 4), 256, 0, stream>>>(Vb, Vtb);
  attn_flash<<<dim3(16, 16, 4), 512, 0, stream>>>(Qb, Kb, Vtb, Yb);

  gemm_o<<<dim3(64, 8), 256, 0, stream>>>(Yb, wob, out);
}

// Round 5
// 298.115 us; speedup vs baseline: 1.0334x; 1.0334x over previous
//
#include <hip/hip_runtime.h>

typedef __bf16 bf16;
typedef bf16  bf16x8 __attribute__((ext_vector_type(8)));
typedef bf16  bf16x4 __attribute__((ext_vector_type(4)));
typedef short s16x4  __attribute__((ext_vector_type(4)));
typedef float f32x4  __attribute__((ext_vector_type(4)));

#define AS1 __attribute__((address_space(1)))
#define AS3 __attribute__((address_space(3)))

#define SQLEN 2048
#define EMB   1024

// ---------------- fp32 -> bf16 convert (memory-bound) ----------------
__global__ __launch_bounds__(256) void cvt_f32_bf16(const float* __restrict__ in,
                                                    bf16* __restrict__ out, int n8) {
  int i = blockIdx.x * blockDim.x + threadIdx.x;
  if (i >= n8) return;
  const float4* p = (const float4*)in + (size_t)i * 2;
  float4 a = p[0], b = p[1];
  bf16x8 o;
  o[0] = (bf16)a.x; o[1] = (bf16)a.y; o[2] = (bf16)a.z; o[3] = (bf16)a.w;
  o[4] = (bf16)b.x; o[5] = (bf16)b.y; o[6] = (bf16)b.z; o[7] = (bf16)b.w;
  *((bf16x8*)out + i) = o;
}

// 4 weight matrices in one dispatch (blockIdx.y selects)
__global__ __launch_bounds__(256) void cvt_w4(const float* __restrict__ w0, const float* __restrict__ w1,
                                              const float* __restrict__ w2, const float* __restrict__ w3,
                                              bf16* o0, bf16* o1, bf16* o2, bf16* o3, int n8) {
  const float* in; bf16* out;
  switch (blockIdx.y) {
    case 0: in = w0; out = o0; break;
    case 1: in = w1; out = o1; break;
    case 2: in = w2; out = o2; break;
    default: in = w3; out = o3; break;
  }
  int i = blockIdx.x * blockDim.x + threadIdx.x;
  if (i >= n8) return;
  const float4* p = (const float4*)in + (size_t)i * 2;
  float4 a = p[0], b = p[1];
  bf16x8 o;
  o[0] = (bf16)a.x; o[1] = (bf16)a.y; o[2] = (bf16)a.z; o[3] = (bf16)a.w;
  o[4] = (bf16)b.x; o[5] = (bf16)b.y; o[6] = (bf16)b.z; o[7] = (bf16)b.w;
  *((bf16x8*)out + i) = o;
}

// ---------------- V transpose: Vb[b*2048+t][n] -> Vt[(b*1024+n)][t] ----------
__global__ __launch_bounds__(256) void transpose_v(const bf16* __restrict__ Vb,
                                                   bf16* __restrict__ Vt) {
  __shared__ bf16 T[64][72];
  const int b = blockIdx.z;
  const int t0 = blockIdx.x * 64, n0 = blockIdx.y * 64;
  const int r = threadIdx.x >> 3, c = threadIdx.x & 7;
#pragma unroll
  for (int i = 0; i < 2; ++i) {
    const int row = i * 32 + r;
    *(bf16x8*)&T[row][c * 8] =
        *(const bf16x8*)&Vb[((size_t)(b * SQLEN + t0 + row)) * EMB + n0 + c * 8];
  }
  __syncthreads();
#pragma unroll
  for (int i = 0; i < 2; ++i) {
    const int n = i * 32 + r;
    bf16x8 o;
#pragma unroll
    for (int j = 0; j < 8; ++j) o[j] = T[c * 8 + j][n];
    *(bf16x8*)&Vt[((size_t)(b * EMB + n0 + n)) * SQLEN + t0 + c * 8] = o;
  }
}

// ---------------- NT GEMM body: C[M,N] = A[M,K]*B[N,K]^T, dbuf single-barrier K-loop
template <int OUTF32>
__device__ __forceinline__
void gemm_body(const bf16* __restrict__ A, const bf16* __restrict__ B,
               float* __restrict__ Cf, bf16* __restrict__ Cb,
               int M, int N, int K, float scale, bf16* Asl, bf16* Bsl) {
  const int tid  = threadIdx.x;
  const int lane = tid & 63, wave = tid >> 6;
  const int quad = lane >> 4, col = lane & 15;
  const int m0 = blockIdx.x * 128, n0 = blockIdx.y * 128;
  const int wr = wave >> 1, wc = wave & 1;

  f32x4 acc[4][4];
  const f32x4 fz = {0.f, 0.f, 0.f, 0.f};
#pragma unroll
  for (int i = 0; i < 4; ++i)
#pragma unroll
    for (int j = 0; j < 4; ++j) acc[i][j] = fz;

  const int srow = lane >> 2;
  const int sk   = lane & 3;

  auto stage = [&](int buf, int k0) {
#pragma unroll
    for (int r = 0; r < 2; ++r) {
      const int c      = wave * 2 + r;
      const int row    = c * 16 + srow;
      const int gchunk = sk ^ (row & 3);
      const bf16* ga = A + (size_t)(m0 + row) * K + k0 + gchunk * 8;
      const bf16* gb = B + (size_t)(n0 + row) * K + k0 + gchunk * 8;
      __builtin_amdgcn_global_load_lds((const AS1 void*)ga, (AS3 void*)(Asl + buf * 4096 + c * 512), 16, 0, 0);
      __builtin_amdgcn_global_load_lds((const AS1 void*)gb, (AS3 void*)(Bsl + buf * 4096 + c * 512), 16, 0, 0);
    }
  };

  const int nk = K >> 5;
  stage(0, 0);
  for (int it = 0; it < nk; ++it) {
    __syncthreads();
    if (it + 1 < nk) stage((it + 1) & 1, (it + 1) << 5);
    const bf16* As = Asl + (it & 1) * 4096;
    const bf16* Bs = Bsl + (it & 1) * 4096;

    bf16x8 af[4], bfr[4];
#pragma unroll
    for (int i = 0; i < 4; ++i) {
      const int r = wr * 64 + i * 16 + col;
      af[i] = *(const bf16x8*)&As[r * 32 + ((quad ^ (col & 3)) * 8)];
    }
#pragma unroll
    for (int j = 0; j < 4; ++j) {
      const int r = wc * 64 + j * 16 + col;
      bfr[j] = *(const bf16x8*)&Bs[r * 32 + ((quad ^ (col & 3)) * 8)];
    }
#pragma unroll
    for (int i = 0; i < 4; ++i)
#pragma unroll
      for (int j = 0; j < 4; ++j)
        acc[i][j] = __builtin_amdgcn_mfma_f32_16x16x32_bf16(af[i], bfr[j], acc[i][j], 0, 0, 0);
  }

#pragma unroll
  for (int i = 0; i < 4; ++i) {
#pragma unroll
    for (int j = 0; j < 4; ++j) {
      const int gm0 = m0 + wr * 64 + i * 16 + quad * 4;
      const int gn  = n0 + wc * 64 + j * 16 + col;
#pragma unroll
      for (int r = 0; r < 4; ++r) {
        const size_t idx = (size_t)(gm0 + r) * N + gn;
        if (OUTF32) Cf[idx] = acc[i][j][r] * scale;
        else        Cb[idx] = (bf16)(acc[i][j][r] * scale);
      }
    }
  }
}

// fused Q/K/V projection: blockIdx.z selects weight/output
__global__ __launch_bounds__(256, 2)
void gemm_qkv(const bf16* __restrict__ A, const bf16* __restrict__ Wq,
              const bf16* __restrict__ Wk, const bf16* __restrict__ Wv,
              bf16* Qo, bf16* Ko, bf16* Vo, float qscale) {
  __shared__ bf16 Asl[2 * 4096];
  __shared__ bf16 Bsl[2 * 4096];
  const bf16* B; bf16* C; float sc = 1.0f;
  if (blockIdx.z == 0)      { B = Wq; C = Qo; sc = qscale; }
  else if (blockIdx.z == 1) { B = Wk; C = Ko; }
  else                      { B = Wv; C = Vo; }
  gemm_body<0>(A, B, nullptr, C, 8192, 1024, 1024, sc, Asl, Bsl);
}

__global__ __launch_bounds__(256, 2)
void gemm_o(const bf16* __restrict__ A, const bf16* __restrict__ W, float* __restrict__ C) {
  __shared__ bf16 Asl[2 * 4096];
  __shared__ bf16 Bsl[2 * 4096];
  gemm_body<1>(A, W, C, nullptr, 8192, 1024, 1024, 1.0f, Asl, Bsl);
}

// ---------------- flash causal attention, S^T + 2 q-strips per wave ----------------
// Q pre-scaled by 0.125*log2(e). Vt: [(b*1024+n), t]. Block = 4 waves, each wave
// owns 32 q (strips at wave*16 and 64+wave*16); K/V frag LDS reads are reused in
// registers across both strips -> LDS-pipe demand per MFMA halved vs R4.
__global__ __launch_bounds__(256, 3)
void attn_flash(const bf16* __restrict__ Q, const bf16* __restrict__ K,
                const bf16* __restrict__ Vt, bf16* __restrict__ Y) {
  __shared__ bf16 Qs[128 * 64];
  __shared__ bf16 Ksb[2][64 * 64];
  __shared__ bf16 Vsb[2][64 * 64];
  // LDS = 16K + 16K + 16K = 48KB -> 3 blocks/CU (12 waves/CU)

  const int tid  = threadIdx.x;
  const int lane = tid & 63, wave = tid >> 6;   // wave 0..3
  const int quad = lane >> 4, col = lane & 15;
  const int qt = 15 - blockIdx.x;  // longest blocks first
  const int h  = blockIdx.y;
  const int b  = blockIdx.z;
  const int q0 = qt * 128;
  const int hc = h * 64;
  const size_t rowBase = (size_t)b * SQLEN;

  const int srow8 = lane >> 3;
  const int sch   = lane & 7;
  const int gch   = sch ^ srow8;   // XOR-8 swizzled global chunk
  const int a7    = col & 7;

  auto stageKV = [&](int buf, int t0) {
#pragma unroll
    for (int i = 0; i < 2; ++i) {
      const int c  = wave * 2 + i;
      const int rr = c * 8 + srow8;
      const bf16* gk = K + (rowBase + t0 + rr) * EMB + hc + gch * 8;
      const bf16* gv = Vt + ((size_t)(b * EMB + hc + rr)) * SQLEN + t0 + gch * 8;
      __builtin_amdgcn_global_load_lds((const AS1 void*)gk, (AS3 void*)(&Ksb[buf][c * 512]), 16, 0, 0);
      __builtin_amdgcn_global_load_lds((const AS1 void*)gv, (AS3 void*)(&Vsb[buf][c * 512]), 16, 0, 0);
    }
  };

  // ---- prologue: stage Q (128 rows) + first K/V tile ----
#pragma unroll
  for (int i = 0; i < 4; ++i) {
    const int c  = wave * 4 + i;       // 0..15
    const int rr = c * 8 + srow8;
    const bf16* g = Q + (rowBase + q0 + rr) * EMB + hc + gch * 8;
    __builtin_amdgcn_global_load_lds((const AS1 void*)g, (AS3 void*)(&Qs[c * 512]), 16, 0, 0);
  }
  stageKV(0, 0);
  __syncthreads();

  // Q fragments for both strips (strip g owns q = q0 + g*64 + wave*16 + col)
  bf16x8 qf[2][2];
#pragma unroll
  for (int g = 0; g < 2; ++g) {
    const int row = g * 64 + wave * 16 + col;
    qf[g][0] = *(const bf16x8*)&Qs[row * 64 + ((quad ^ a7) * 8)];
    qf[g][1] = *(const bf16x8*)&Qs[row * 64 + (((quad ^ 4) ^ a7) * 8)];
  }

  float m_i[2] = {-INFINITY, -INFINITY}, l_i[2] = {0.f, 0.f};
  f32x4 o[2][4];
  const f32x4 fz = {0.f, 0.f, 0.f, 0.f};
#pragma unroll
  for (int g = 0; g < 2; ++g)
#pragma unroll
    for (int dd = 0; dd < 4; ++dd) o[g][dd] = fz;

  const int ntt = 2 * qt + 2;
  for (int tt = 0; tt < ntt; ++tt) {
    const int t0 = tt * 64;
    const int cur = tt & 1;
    if (tt + 1 < ntt) stageKV(cur ^ 1, t0 + 64);  // prefetch in flight across iter
    const bf16* Ks = Ksb[cur];
    const bf16* Vs = Vsb[cur];

    // ---- S^T slabs for both strips; kf loaded ONCE, reused across strips ----
    f32x4 s[2][4];
#pragma unroll
    for (int sl = 0; sl < 4; ++sl) {
      const bf16x8 kf0 = *(const bf16x8*)&Ks[(sl * 16 + col) * 64 + ((quad ^ a7) * 8)];
      const bf16x8 kf1 = *(const bf16x8*)&Ks[(sl * 16 + col) * 64 + (((quad ^ 4) ^ a7) * 8)];
#pragma unroll
      for (int g = 0; g < 2; ++g) {
        f32x4 z = fz;
        z = __builtin_amdgcn_mfma_f32_16x16x32_bf16(kf0, qf[g][0], z, 0, 0, 0);
        s[g][sl] = __builtin_amdgcn_mfma_f32_16x16x32_bf16(kf1, qf[g][1], z, 0, 0, 0);
      }
    }

    if (tt >= 2 * qt) {  // diagonal region: global-index causal mask
#pragma unroll
      for (int g = 0; g < 2; ++g) {
        const int qg = q0 + g * 64 + wave * 16 + col;
#pragma unroll
        for (int sl = 0; sl < 4; ++sl)
#pragma unroll
          for (int r = 0; r < 4; ++r)
            if (t0 + sl * 16 + quad * 4 + r > qg) s[g][sl][r] = -INFINITY;
      }
    }

    // ---- online softmax per strip (independent chains -> ILP) ----
    bf16x4 pb[2][4];
    float alpha[2];
#pragma unroll
    for (int g = 0; g < 2; ++g) {
      float mx = s[g][0][0];
#pragma unroll
      for (int sl = 0; sl < 4; ++sl)
#pragma unroll
        for (int r = 0; r < 4; ++r) mx = fmaxf(mx, s[g][sl][r]);
      mx = fmaxf(mx, __shfl_xor(mx, 16));
      mx = fmaxf(mx, __shfl_xor(mx, 32));
      const float mnew = fmaxf(m_i[g], mx);
      alpha[g] = __builtin_amdgcn_exp2f(m_i[g] - mnew);
      float rs = 0.f;
#pragma unroll
      for (int sl = 0; sl < 4; ++sl)
#pragma unroll
        for (int r = 0; r < 4; ++r) {
          const float p = __builtin_amdgcn_exp2f(s[g][sl][r] - mnew);
          rs += p;
          pb[g][sl][r] = (bf16)p;
        }
      rs += __shfl_xor(rs, 16);
      rs += __shfl_xor(rs, 32);
      l_i[g] = l_i[g] * alpha[g] + rs;
      m_i[g] = mnew;
    }
#pragma unroll
    for (int g = 0; g < 2; ++g)
#pragma unroll
      for (int dd = 0; dd < 4; ++dd) o[g][dd] *= alpha[g];

    // ---- O^T += V^T P^T; vb loaded ONCE, reused across strips ----
#pragma unroll
    for (int sl = 0; sl < 4; ++sl) {
      const s16x4 pf0 = __builtin_bit_cast(s16x4, pb[0][sl]);
      const s16x4 pf1 = __builtin_bit_cast(s16x4, pb[1][sl]);
      const int cch  = 2 * sl + (quad >> 1);
      const int half = quad & 1;
#pragma unroll
      for (int dd = 0; dd < 4; ++dd) {
        const int row = dd * 16 + col;
        const bf16x4 vb = *(const bf16x4*)&Vs[row * 64 + ((cch ^ a7) * 8) + half * 4];
        const s16x4 vf = __builtin_bit_cast(s16x4, vb);
        o[0][dd] = __builtin_amdgcn_mfma_f32_16x16x16bf16_1k(vf, pf0, o[0][dd], 0, 0, 0);
        o[1][dd] = __builtin_amdgcn_mfma_f32_16x16x16bf16_1k(vf, pf1, o[1][dd], 0, 0, 0);
      }
    }
    __syncthreads();  // drains prefetch; guards dbuf reuse
  }

  // ---- epilogue: per strip, O^T/l -> per-wave LDS transpose -> coalesced store ----
  bf16* Ot = &Ksb[0][0] + wave * 1280;  // wave-private 16x72 region (dead Ksb)
#pragma unroll
  for (int g = 0; g < 2; ++g) {
    const float rl = __builtin_amdgcn_rcpf(l_i[g]);
#pragma unroll
    for (int dd = 0; dd < 4; ++dd) {
      bf16x4 ob;
#pragma unroll
      for (int r = 0; r < 4; ++r) ob[r] = (bf16)(o[g][dd][r] * rl);
      *(bf16x4*)&Ot[col * 72 + dd * 16 + quad * 4] = ob;
    }
    // same-wave LDS write->read: compiler orders via lgkmcnt, no barrier needed
#pragma unroll
    for (int i = 0; i < 2; ++i) {
      const int row = i * 8 + srow8;
      const bf16x8 v = *(const bf16x8*)&Ot[row * 72 + sch * 8];
      *(bf16x8*)&Y[(rowBase + q0 + g * 64 + wave * 16 + row) * EMB + hc + sch * 8] = v;
    }
  }
}

// ---------------- launcher ----------------
extern "C" void kernel_launch(void* const* d_in, const int* in_sizes, int n_in,
                              void* d_out, int out_size, void* d_ws, size_t ws_size,
                              hipStream_t stream) {
  const float* x  = (const float*)d_in[0];
  const float* Wq = (const float*)d_in[1];
  const float* Wk = (const float*)d_in[2];
  const float* Wv = (const float*)d_in[3];
  const float* Wo = (const float*)d_in[4];
  float* out = (float*)d_out;

  const size_t ME = 8192ull * 1024ull;
  const size_t WE = 1024ull * 1024ull;
  bf16* ws  = (bf16*)d_ws;
  bf16* xb  = ws;
  bf16* wqb = xb + ME;
  bf16* wkb = wqb + WE;
  bf16* wvb = wkb + WE;
  bf16* wob = wvb + WE;
  bf16* Qb  = wob + WE;
  bf16* Kb  = Qb + ME;
  bf16* Vb  = Kb + ME;
  bf16* Yb  = Vb + ME;
  bf16* Vtb = xb;        // Vt aliases xb (dead after QKV GEMM)

  cvt_f32_bf16<<<(int)(ME / 8 / 256), 256, 0, stream>>>(x, xb, (int)(ME / 8));
  cvt_w4<<<dim3((int)(WE / 8 / 256), 4), 256, 0, stream>>>(Wq, Wk, Wv, Wo, wqb, wkb, wvb, wob, (int)(WE / 8));

  const float qscale = 0.125f * 1.4426950408889634f;
  gemm_qkv<<<dim3(64, 8, 3), 256, 0, stream>>>(xb, wqb, wkb, wvb, Qb, Kb, Vb, qscale);

  transpose_v<<<dim3(32, 16, 4), 256, 0, stream>>>(Vb, Vtb);
  attn_flash<<<dim3(16, 16, 4), 256, 0, stream>>>(Qb, Kb, Vtb, Yb);

  gemm_o<<<dim3(64, 8), 256, 0, stream>>>(Yb, wob, out);
}